// Round 25
// baseline (519.648 us; speedup 1.0000x reference)
//
#include <hip/hip_runtime.h>
#include <hip/hip_bf16.h>

typedef float    f32x4 __attribute__((ext_vector_type(4)));
typedef short    s16x8 __attribute__((ext_vector_type(8)));
typedef unsigned u32x4 __attribute__((ext_vector_type(4)));

#define LOG2E 1.44269504088896340736f
#define LN2   0.69314718055994530942f

__device__ __forceinline__ unsigned short f2bf(float f) {
    union { __hip_bfloat16 b; unsigned short u; } v;
    v.b = __float2bfloat16(f);
    return v.u;
}
// HW packed f32->bf16 (RTNE, same as __float2bfloat16): 2 converts / 1 op.
__device__ __forceinline__ unsigned cvtpk(float lo, float hi) {
    unsigned r;
    asm("v_cvt_pk_bf16_f32 %0, %1, %2" : "=v"(r) : "v"(lo), "v"(hi));
    return r;
}
// raw v_exp_f32: computes 2^x (no log2e premultiply — folded into weights)
__device__ __forceinline__ float exp2f_raw(float x) {
    float r;
    asm("v_exp_f32 %0, %1" : "=v"(r) : "v"(x));
    return r;
}
// sigmoid for PRE-SCALED input (x already times log2e)
__device__ __forceinline__ float sig2f(float x) {
    return __builtin_amdgcn_rcpf(1.0f + exp2f_raw(-x));
}

__device__ __forceinline__ s16x8 pack8(float4 a, float4 b) {
    union { u32x4 u; s16x8 v; } r;
    r.u[0] = cvtpk(a.x, a.y);
    r.u[1] = cvtpk(a.z, a.w);
    r.u[2] = cvtpk(b.x, b.y);
    r.u[3] = cvtpk(b.z, b.w);
    return r.v;
}

// ---------------------------------------------------------------------------
// Kernel 1: convert atom_fea fp32 -> bf16, rows PERMUTED into B-fragment
// split-half order: Af[a][(kh*4+q)*8 + jj] = bf16(atom[a][kh*32 + q*4 +
// (jj&3) + (jj>=4 ? 16 : 0)]).  Each lane's fragment = one 16 B load.
// ---------------------------------------------------------------------------
__global__ __launch_bounds__(256) void atom_conv_kernel(
    const float* __restrict__ atom_fea, unsigned short* __restrict__ Af, int total)
{
    int i = blockIdx.x * blockDim.x + threadIdx.x;
    const int stride = gridDim.x * blockDim.x;
    for (; i < total; i += stride) {
        int a = i >> 6, p = i & 63;
        int kh = p >> 5, q = (p >> 3) & 3, jj = p & 7;
        int k = kh * 32 + q * 4 + (jj & 3) + ((jj & 4) ? 16 : 0);
        Af[i] = f2bf(atom_fea[(size_t)a * 64 + k]);
    }
}

// ---------------------------------------------------------------------------
// Kernel 2: R25 = R23/R24 geometry (1024-thr block, 16 waves co-resident —
// proven 46.6% occupancy) + amdgpu_waves_per_eu(4,4): pins the backend's
// occupancy TARGET to 4 waves/EU so the register allocator budgets 512/4 =
// 128 VGPR (>= demand ~108, no spill). R23/R24 showed the allocator was
// targeting 8 waves/EU (2-block fit at 41 KB LDS) -> 64 VGPR -> 123 MB of
// scratch; R24's LDS pad got DCE'd (LDS stayed 41984). This attribute is
// the direct knob. Gates: VGPR >= 100 (64 = ignored -> revert to R21 and
// declare floor); WRITE == 400.0 MB.
// ---------------------------------------------------------------------------
#define NCH 40

__global__ __launch_bounds__(1024)
__attribute__((amdgpu_waves_per_eu(4, 4)))
void edge_kernel(
    const unsigned short* __restrict__ Af,
    const float* __restrict__ edge_ij,
    const int*   __restrict__ nbr,
    const float* __restrict__ bonds_r,
    const float* __restrict__ W1, const float* __restrict__ b1,
    const float* __restrict__ W2, const float* __restrict__ b2,
    const float* __restrict__ W3, const float* __restrict__ b3,
    const float* __restrict__ Wr, const float* __restrict__ br,
    float* __restrict__ out, int n_edges)
{
    __shared__ unsigned short wlds[NCH * 512];   // 40 KiB: W1 all + W2 atom
    __shared__ float blds[256];                  // scaled biases

    const int t    = threadIdx.x;
    const int wave = t >> 6;
    const int lane = t & 63;
    const int q    = lane >> 4;
    const int n    = lane & 15;

    // ---- stage W1 (24 chunks) + W2 atom-part (16 chunks), x log2e ----
    if (t < 256) {
        for (int ch = 0; ch < NCH; ++ch) {
            int idx = t * 2;
            #pragma unroll
            for (int e2 = 0; e2 < 2; ++e2, ++idx) {
                const int l  = idx >> 3, j = idx & 7;
                const int lq = l >> 4, ln = l & 15;
                const int kk = (j < 4) ? (lq * 4 + j) : (16 + lq * 4 + (j - 4));
                float val;
                if (ch < 24) {                       // W1: kh 0..5, nb 0..3
                    int kh = ch >> 2, nb = ch & 3;
                    val = W1[(size_t)(kh * 32 + kk) * 64 + nb * 16 + ln];
                } else {                             // W2 atom part: kh 0..3
                    int c2 = ch - 24; int kh = c2 >> 2, nb = c2 & 3;
                    val = W2[(size_t)(kh * 32 + kk) * 64 + nb * 16 + ln];
                }
                wlds[ch * 512 + idx] = f2bf(val * LOG2E);
            }
        }
        if (t < 64)        blds[t] = b1[t] * LOG2E;
        else if (t < 128)  blds[t] = b2[t - 64] * LOG2E;
        else if (t < 192)  blds[t] = b3[t - 128] * LOG2E;
        else               blds[t] = br[t - 192] * LN2;
    }

    // ---- W3 (UNSCALED) / Wr (x ln2) / W2-e_ij (x log2e) in registers ----
    s16x8 w3f[8], wrf[4], w2e[8];
    {
        const int ln = lane & 15;
        const int lq = lane >> 4;
        #pragma unroll
        for (int c2 = 0; c2 < 8; ++c2) {
            const int kh = c2 >> 2, nb = c2 & 3;
            s16x8 w, v;
            #pragma unroll
            for (int j = 0; j < 8; ++j) {
                const int kk = (j < 4) ? (lq * 4 + j) : (16 + lq * 4 + (j - 4));
                w[j] = (short)f2bf(W3[(size_t)(kh * 32 + kk) * 64 + nb * 16 + ln]);
                v[j] = (short)f2bf(W2[(size_t)((kh + 4) * 32 + kk) * 64 + nb * 16 + ln] * LOG2E);
            }
            w3f[c2] = w;
            w2e[c2] = v;
        }
        #pragma unroll
        for (int nb = 0; nb < 4; ++nb) {
            s16x8 w;
            #pragma unroll
            for (int j = 0; j < 8; ++j) {
                const int kk = (j < 4) ? (lq * 4 + j) : (16 + lq * 4 + (j - 4));
                w[j] = (short)(kk < 16 ? f2bf(Wr[(size_t)kk * 64 + nb * 16 + ln] * LN2) : 0);
            }
            wrf[nb] = w;
        }
    }
    __syncthreads();

    const int tiles   = (n_edges + 15) >> 4;
    const int tstride = gridDim.x * 16;
    int T = blockIdx.x * 16 + wave;
    if (T >= tiles) return;

    const int2* nb2 = (const int2*)nbr;

    // ---- prologue: gathers for T; streams for T (cur) and T+s (next) ----
    int Tn = T + tstride;
    bool havenext = (Tn < tiles);
    int2 nbc = nb2[min(T * 16 + n, n_edges - 1)];
    int2 nbn = nbc;
    if (havenext) nbn = nb2[min(Tn * 16 + n, n_edges - 1)];

    s16x8 ai0 = *(const s16x8*)&Af[(size_t)nbc.x * 64 + q * 8];
    s16x8 ai1 = *(const s16x8*)&Af[(size_t)nbc.x * 64 + 32 + q * 8];
    s16x8 aj0 = *(const s16x8*)&Af[(size_t)nbc.y * 64 + q * 8];
    s16x8 aj1 = *(const s16x8*)&Af[(size_t)nbc.y * 64 + 32 + q * 8];

    const int e0 = min(T * 16 + n, n_edges - 1);
    const float* xr0 = edge_ij + (size_t)e0 * 64;
    float4 cx0 = *(const float4*)(xr0 +      q * 4);
    float4 cx1 = *(const float4*)(xr0 + 16 + q * 4);
    float4 cx2 = *(const float4*)(xr0 + 32 + q * 4);
    float4 cx3 = *(const float4*)(xr0 + 48 + q * 4);
    float4 cb  = *(const float4*)(bonds_r + (size_t)e0 * 16 + q * 4);

    const int e1 = havenext ? min(Tn * 16 + n, n_edges - 1) : e0;
    const float* xr1 = edge_ij + (size_t)e1 * 64;
    float4 nx0 = *(const float4*)(xr1 +      q * 4);
    float4 nx1 = *(const float4*)(xr1 + 16 + q * 4);
    float4 nx2 = *(const float4*)(xr1 + 32 + q * 4);
    float4 nx3 = *(const float4*)(xr1 + 48 + q * 4);
    float4 nbd = *(const float4*)(bonds_r + (size_t)e1 * 16 + q * 4);

    while (true) {
        const int E0 = T * 16;

        // ---- pack current streams (cx/cb die here -> free for rotation) --
        s16x8 xf0 = pack8(cx0, cx1);
        s16x8 xf1 = pack8(cx2, cx3);
        s16x8 bfrag;
        {
            union { u32x4 u; s16x8 v; } B;
            B.u[0] = cvtpk(cb.x, cb.y);
            B.u[1] = cvtpk(cb.z, cb.w);
            B.u[2] = 0; B.u[3] = 0;
            bfrag = B.v;
        }

        // ---- acc init = scaled biases ----
        f32x4 acc1[4], acc2[4];
        #pragma unroll
        for (int nb = 0; nb < 4; ++nb) {
            acc1[nb] = *(const f32x4*)&blds[nb * 16 + q * 4];
            acc2[nb] = *(const f32x4*)&blds[64 + nb * 16 + q * 4];
        }

        // ---- layer 1, atom part: kh 0..3 ----
        __builtin_amdgcn_s_setprio(1);
        #pragma unroll
        for (int nb = 0; nb < 4; ++nb) {
            s16x8 w;
            w = *(const s16x8*)&wlds[( 0 + nb) * 512 + lane * 8];
            acc1[nb] = __builtin_amdgcn_mfma_f32_16x16x32_bf16(w, ai0, acc1[nb], 0, 0, 0);
            w = *(const s16x8*)&wlds[( 4 + nb) * 512 + lane * 8];
            acc1[nb] = __builtin_amdgcn_mfma_f32_16x16x32_bf16(w, ai1, acc1[nb], 0, 0, 0);
            w = *(const s16x8*)&wlds[( 8 + nb) * 512 + lane * 8];
            acc1[nb] = __builtin_amdgcn_mfma_f32_16x16x32_bf16(w, aj0, acc1[nb], 0, 0, 0);
            w = *(const s16x8*)&wlds[(12 + nb) * 512 + lane * 8];
            acc1[nb] = __builtin_amdgcn_mfma_f32_16x16x32_bf16(w, aj1, acc1[nb], 0, 0, 0);
            w = *(const s16x8*)&wlds[(24 + nb) * 512 + lane * 8];
            acc2[nb] = __builtin_amdgcn_mfma_f32_16x16x32_bf16(w, ai0, acc2[nb], 0, 0, 0);
            w = *(const s16x8*)&wlds[(28 + nb) * 512 + lane * 8];
            acc2[nb] = __builtin_amdgcn_mfma_f32_16x16x32_bf16(w, ai1, acc2[nb], 0, 0, 0);
            w = *(const s16x8*)&wlds[(32 + nb) * 512 + lane * 8];
            acc2[nb] = __builtin_amdgcn_mfma_f32_16x16x32_bf16(w, aj0, acc2[nb], 0, 0, 0);
            w = *(const s16x8*)&wlds[(36 + nb) * 512 + lane * 8];
            acc2[nb] = __builtin_amdgcn_mfma_f32_16x16x32_bf16(w, aj1, acc2[nb], 0, 0, 0);
        }
        __builtin_amdgcn_s_setprio(0);

        // ---- prefetch: gathers T+1 (depth-1); streams depth-2 rotate ----
        const int T2 = Tn + tstride;
        const bool haveT2 = (T2 < tiles);
        s16x8 nai0 = ai0, nai1 = ai1, naj0 = aj0, naj1 = aj1;
        if (havenext) {
            nai0 = *(const s16x8*)&Af[(size_t)nbn.x * 64 + q * 8];
            nai1 = *(const s16x8*)&Af[(size_t)nbn.x * 64 + 32 + q * 8];
            naj0 = *(const s16x8*)&Af[(size_t)nbn.y * 64 + q * 8];
            naj1 = *(const s16x8*)&Af[(size_t)nbn.y * 64 + 32 + q * 8];
            if (haveT2) nbn = nb2[min(T2 * 16 + n, n_edges - 1)];
        }
        cx0 = nx0; cx1 = nx1; cx2 = nx2; cx3 = nx3; cb = nbd;
        if (haveT2) {
            const int e2 = min(T2 * 16 + n, n_edges - 1);
            const float* xr2 = edge_ij + (size_t)e2 * 64;
            nx0 = *(const float4*)(xr2 +      q * 4);
            nx1 = *(const float4*)(xr2 + 16 + q * 4);
            nx2 = *(const float4*)(xr2 + 32 + q * 4);
            nx3 = *(const float4*)(xr2 + 48 + q * 4);
            nbd = *(const float4*)(bonds_r + (size_t)e2 * 16 + q * 4);
        }

        // ---- layer 1, e_ij part: kh 4..5 ----
        __builtin_amdgcn_s_setprio(1);
        #pragma unroll
        for (int nb = 0; nb < 4; ++nb) {
            s16x8 w;
            w = *(const s16x8*)&wlds[(16 + nb) * 512 + lane * 8];
            acc1[nb] = __builtin_amdgcn_mfma_f32_16x16x32_bf16(w, xf0, acc1[nb], 0, 0, 0);
            w = *(const s16x8*)&wlds[(20 + nb) * 512 + lane * 8];
            acc1[nb] = __builtin_amdgcn_mfma_f32_16x16x32_bf16(w, xf1, acc1[nb], 0, 0, 0);
            acc2[nb] = __builtin_amdgcn_mfma_f32_16x16x32_bf16(w2e[nb],     xf0, acc2[nb], 0, 0, 0);
            acc2[nb] = __builtin_amdgcn_mfma_f32_16x16x32_bf16(w2e[4 + nb], xf1, acc2[nb], 0, 0, 0);
        }
        __builtin_amdgcn_s_setprio(0);

        // ---- h (x log2e) lane-local: a1s*rcp((1+2^-a1s)(1+2^-a2s)) ----
        f32x4 h[4];
        #pragma unroll
        for (int nb = 0; nb < 4; ++nb) {
            f32x4 s1 = acc1[nb], s2 = acc2[nb], hv;
            #pragma unroll
            for (int j = 0; j < 4; ++j) {
                float ea = exp2f_raw(-s1[j]);
                float eb = exp2f_raw(-s2[j]);
                hv[j] = s1[j] * __builtin_amdgcn_rcpf((1.0f + ea) * (1.0f + eb));
            }
            h[nb] = hv;
        }
        s16x8 hf0, hf1;
        {
            union { u32x4 u; s16x8 v; } H0, H1;
            H0.u[0] = cvtpk(h[0][0], h[0][1]);
            H0.u[1] = cvtpk(h[0][2], h[0][3]);
            H0.u[2] = cvtpk(h[1][0], h[1][1]);
            H0.u[3] = cvtpk(h[1][2], h[1][3]);
            H1.u[0] = cvtpk(h[2][0], h[2][1]);
            H1.u[1] = cvtpk(h[2][2], h[2][3]);
            H1.u[2] = cvtpk(h[3][0], h[3][1]);
            H1.u[3] = cvtpk(h[3][2], h[3][3]);
            hf0 = H0.v; hf1 = H1.v;
        }

        // ---- layer 2 (h*log2e @ W3 -> a3 pre-scaled) and gate (x ln2) ----
        f32x4 a3[4], g[4];
        #pragma unroll
        for (int nb = 0; nb < 4; ++nb) { a3[nb] = (f32x4){0,0,0,0}; g[nb] = (f32x4){0,0,0,0}; }
        __builtin_amdgcn_s_setprio(1);
        #pragma unroll
        for (int nb = 0; nb < 4; ++nb) {
            a3[nb] = __builtin_amdgcn_mfma_f32_16x16x32_bf16(hf0, w3f[nb],     a3[nb], 0, 0, 0);
            a3[nb] = __builtin_amdgcn_mfma_f32_16x16x32_bf16(hf1, w3f[4 + nb], a3[nb], 0, 0, 0);
            g[nb]  = __builtin_amdgcn_mfma_f32_16x16x32_bf16(bfrag, wrf[nb],   g[nb],  0, 0, 0);
        }
        __builtin_amdgcn_s_setprio(0);

        // ---- out = s_scaled * rcp(1+2^-s_scaled) * g'  (all folds done) --
        float* outp = out + (size_t)(E0 + q * 4) * 64 + n;
        if (E0 + 16 <= n_edges) {
            #pragma unroll
            for (int nb = 0; nb < 4; ++nb) {
                const float b3s = blds[128 + nb * 16 + n];
                const float brs = blds[192 + nb * 16 + n];
                f32x4 s  = a3[nb] + b3s;
                f32x4 gg = g[nb] + brs;
                f32x4 o;
                #pragma unroll
                for (int j = 0; j < 4; ++j)
                    o[j] = s[j] * sig2f(s[j]) * gg[j];
                #pragma unroll
                for (int j = 0; j < 4; ++j)
                    outp[j * 64 + nb * 16] = o[j];
            }
        } else {
            #pragma unroll
            for (int nb = 0; nb < 4; ++nb) {
                const float b3s = blds[128 + nb * 16 + n];
                const float brs = blds[192 + nb * 16 + n];
                f32x4 s  = a3[nb] + b3s;
                f32x4 gg = g[nb] + brs;
                #pragma unroll
                for (int j = 0; j < 4; ++j)
                    if (E0 + q * 4 + j < n_edges)
                        outp[j * 64 + nb * 16] = s[j] * sig2f(s[j]) * gg[j];
            }
        }

        if (!havenext) break;
        // ---- advance ----
        T = Tn;
        Tn = T2;
        havenext = (Tn < tiles);
        ai0 = nai0; ai1 = nai1; aj0 = naj0; aj1 = naj1;
    }
}

// ---------------------------------------------------------------------------
extern "C" void kernel_launch(void* const* d_in, const int* in_sizes, int n_in,
                              void* d_out, int out_size, void* d_ws, size_t ws_size,
                              hipStream_t stream) {
    const float* atom_fea = (const float*)d_in[0];
    const float* edge_ij  = (const float*)d_in[1];
    const int*   nbr      = (const int*)  d_in[2];
    const float* bonds_r  = (const float*)d_in[3];
    const float* W1 = (const float*)d_in[4];
    const float* b1 = (const float*)d_in[5];
    const float* W2 = (const float*)d_in[6];
    const float* b2 = (const float*)d_in[7];
    const float* Wr = (const float*)d_in[8];
    const float* br = (const float*)d_in[9];
    const float* W3 = (const float*)d_in[10];
    const float* b3 = (const float*)d_in[11];
    float* out = (float*)d_out;
    unsigned short* Af = (unsigned short*)d_ws;   // 50000*64 bf16 = 6.4 MB

    const int n_atoms = in_sizes[0] / 64;
    const int n_edges = in_sizes[2] / 2;

    hipLaunchKernelGGL(atom_conv_kernel, dim3(2048), dim3(256), 0, stream,
                       atom_fea, Af, n_atoms * 64);

    hipLaunchKernelGGL(edge_kernel, dim3(256), dim3(1024), 0, stream,
                       Af, edge_ij, nbr, bonds_r,
                       W1, b1, W2, b2, W3, b3, Wr, br, out, n_edges);
}

// Round 26
// 519.159 us; speedup vs baseline: 1.0009x; 1.0009x over previous
//
#include <hip/hip_runtime.h>
#include <hip/hip_bf16.h>

typedef float    f32x4 __attribute__((ext_vector_type(4)));
typedef short    s16x8 __attribute__((ext_vector_type(8)));
typedef unsigned u32x4 __attribute__((ext_vector_type(4)));

#define LOG2E 1.44269504088896340736f
#define LN2   0.69314718055994530942f

__device__ __forceinline__ unsigned short f2bf(float f) {
    union { __hip_bfloat16 b; unsigned short u; } v;
    v.b = __float2bfloat16(f);
    return v.u;
}
// HW packed f32->bf16 (RTNE, same as __float2bfloat16): 2 converts / 1 op.
__device__ __forceinline__ unsigned cvtpk(float lo, float hi) {
    unsigned r;
    asm("v_cvt_pk_bf16_f32 %0, %1, %2" : "=v"(r) : "v"(lo), "v"(hi));
    return r;
}
// raw v_exp_f32: computes 2^x (no log2e premultiply — folded into weights)
__device__ __forceinline__ float exp2f_raw(float x) {
    float r;
    asm("v_exp_f32 %0, %1" : "=v"(r) : "v"(x));
    return r;
}
// sigmoid for PRE-SCALED input (x already times log2e)
__device__ __forceinline__ float sig2f(float x) {
    return __builtin_amdgcn_rcpf(1.0f + exp2f_raw(-x));
}

__device__ __forceinline__ s16x8 pack8(float4 a, float4 b) {
    union { u32x4 u; s16x8 v; } r;
    r.u[0] = cvtpk(a.x, a.y);
    r.u[1] = cvtpk(a.z, a.w);
    r.u[2] = cvtpk(b.x, b.y);
    r.u[3] = cvtpk(b.z, b.w);
    return r.v;
}

// ---------------------------------------------------------------------------
// Kernel 1: convert atom_fea fp32 -> bf16, rows PERMUTED into B-fragment
// split-half order: Af[a][(kh*4+q)*8 + jj] = bf16(atom[a][kh*32 + q*4 +
// (jj&3) + (jj>=4 ? 16 : 0)]).  Each lane's fragment = one 16 B load.
// ---------------------------------------------------------------------------
__global__ __launch_bounds__(256) void atom_conv_kernel(
    const float* __restrict__ atom_fea, unsigned short* __restrict__ Af, int total)
{
    int i = blockIdx.x * blockDim.x + threadIdx.x;
    const int stride = gridDim.x * blockDim.x;
    for (; i < total; i += stride) {
        int a = i >> 6, p = i & 63;
        int kh = p >> 5, q = (p >> 3) & 3, jj = p & 7;
        int k = kh * 32 + q * 4 + (jj & 3) + ((jj & 4) ? 16 : 0);
        Af[i] = f2bf(atom_fea[(size_t)a * 64 + k]);
    }
}

// ---------------------------------------------------------------------------
// Kernel 2: R26 = R25 geometry/body with amdgpu_num_vgpr(128): the DIRECT
// VGPR allocation request (not an occupancy hint). 128 x 4 waves/SIMD = 512
// = full file, so the 16-wave block still launches; demand ~108 <= 128 ->
// no spill. History: (1024,*) geometry clamps VGPR to 64 via launch-bounds
// min (R23), LDS pad (R24, DCE'd), waves_per_eu(4,4) (R25, parsed but VGPR
// unchanged). If THIS reads back 64, the toolchain has no path to
// 16-waves-no-spill -> revert to R21 (243.8 us) and declare floor.
// Gates: VGPR >= 100; WRITE == 400.0 MB.
// ---------------------------------------------------------------------------
#define NCH 40

__global__ __launch_bounds__(1024)
__attribute__((amdgpu_num_vgpr(128)))
void edge_kernel(
    const unsigned short* __restrict__ Af,
    const float* __restrict__ edge_ij,
    const int*   __restrict__ nbr,
    const float* __restrict__ bonds_r,
    const float* __restrict__ W1, const float* __restrict__ b1,
    const float* __restrict__ W2, const float* __restrict__ b2,
    const float* __restrict__ W3, const float* __restrict__ b3,
    const float* __restrict__ Wr, const float* __restrict__ br,
    float* __restrict__ out, int n_edges)
{
    __shared__ unsigned short wlds[NCH * 512];   // 40 KiB: W1 all + W2 atom
    __shared__ float blds[256];                  // scaled biases

    const int t    = threadIdx.x;
    const int wave = t >> 6;
    const int lane = t & 63;
    const int q    = lane >> 4;
    const int n    = lane & 15;

    // ---- stage W1 (24 chunks) + W2 atom-part (16 chunks), x log2e ----
    if (t < 256) {
        for (int ch = 0; ch < NCH; ++ch) {
            int idx = t * 2;
            #pragma unroll
            for (int e2 = 0; e2 < 2; ++e2, ++idx) {
                const int l  = idx >> 3, j = idx & 7;
                const int lq = l >> 4, ln = l & 15;
                const int kk = (j < 4) ? (lq * 4 + j) : (16 + lq * 4 + (j - 4));
                float val;
                if (ch < 24) {                       // W1: kh 0..5, nb 0..3
                    int kh = ch >> 2, nb = ch & 3;
                    val = W1[(size_t)(kh * 32 + kk) * 64 + nb * 16 + ln];
                } else {                             // W2 atom part: kh 0..3
                    int c2 = ch - 24; int kh = c2 >> 2, nb = c2 & 3;
                    val = W2[(size_t)(kh * 32 + kk) * 64 + nb * 16 + ln];
                }
                wlds[ch * 512 + idx] = f2bf(val * LOG2E);
            }
        }
        if (t < 64)        blds[t] = b1[t] * LOG2E;
        else if (t < 128)  blds[t] = b2[t - 64] * LOG2E;
        else if (t < 192)  blds[t] = b3[t - 128] * LOG2E;
        else               blds[t] = br[t - 192] * LN2;
    }

    // ---- W3 (UNSCALED) / Wr (x ln2) / W2-e_ij (x log2e) in registers ----
    s16x8 w3f[8], wrf[4], w2e[8];
    {
        const int ln = lane & 15;
        const int lq = lane >> 4;
        #pragma unroll
        for (int c2 = 0; c2 < 8; ++c2) {
            const int kh = c2 >> 2, nb = c2 & 3;
            s16x8 w, v;
            #pragma unroll
            for (int j = 0; j < 8; ++j) {
                const int kk = (j < 4) ? (lq * 4 + j) : (16 + lq * 4 + (j - 4));
                w[j] = (short)f2bf(W3[(size_t)(kh * 32 + kk) * 64 + nb * 16 + ln]);
                v[j] = (short)f2bf(W2[(size_t)((kh + 4) * 32 + kk) * 64 + nb * 16 + ln] * LOG2E);
            }
            w3f[c2] = w;
            w2e[c2] = v;
        }
        #pragma unroll
        for (int nb = 0; nb < 4; ++nb) {
            s16x8 w;
            #pragma unroll
            for (int j = 0; j < 8; ++j) {
                const int kk = (j < 4) ? (lq * 4 + j) : (16 + lq * 4 + (j - 4));
                w[j] = (short)(kk < 16 ? f2bf(Wr[(size_t)kk * 64 + nb * 16 + ln] * LN2) : 0);
            }
            wrf[nb] = w;
        }
    }
    __syncthreads();

    const int tiles   = (n_edges + 15) >> 4;
    const int tstride = gridDim.x * 16;
    int T = blockIdx.x * 16 + wave;
    if (T >= tiles) return;

    const int2* nb2 = (const int2*)nbr;

    // ---- prologue: gathers for T; streams for T (cur) and T+s (next) ----
    int Tn = T + tstride;
    bool havenext = (Tn < tiles);
    int2 nbc = nb2[min(T * 16 + n, n_edges - 1)];
    int2 nbn = nbc;
    if (havenext) nbn = nb2[min(Tn * 16 + n, n_edges - 1)];

    s16x8 ai0 = *(const s16x8*)&Af[(size_t)nbc.x * 64 + q * 8];
    s16x8 ai1 = *(const s16x8*)&Af[(size_t)nbc.x * 64 + 32 + q * 8];
    s16x8 aj0 = *(const s16x8*)&Af[(size_t)nbc.y * 64 + q * 8];
    s16x8 aj1 = *(const s16x8*)&Af[(size_t)nbc.y * 64 + 32 + q * 8];

    const int e0 = min(T * 16 + n, n_edges - 1);
    const float* xr0 = edge_ij + (size_t)e0 * 64;
    float4 cx0 = *(const float4*)(xr0 +      q * 4);
    float4 cx1 = *(const float4*)(xr0 + 16 + q * 4);
    float4 cx2 = *(const float4*)(xr0 + 32 + q * 4);
    float4 cx3 = *(const float4*)(xr0 + 48 + q * 4);
    float4 cb  = *(const float4*)(bonds_r + (size_t)e0 * 16 + q * 4);

    const int e1 = havenext ? min(Tn * 16 + n, n_edges - 1) : e0;
    const float* xr1 = edge_ij + (size_t)e1 * 64;
    float4 nx0 = *(const float4*)(xr1 +      q * 4);
    float4 nx1 = *(const float4*)(xr1 + 16 + q * 4);
    float4 nx2 = *(const float4*)(xr1 + 32 + q * 4);
    float4 nx3 = *(const float4*)(xr1 + 48 + q * 4);
    float4 nbd = *(const float4*)(bonds_r + (size_t)e1 * 16 + q * 4);

    while (true) {
        const int E0 = T * 16;

        // ---- pack current streams (cx/cb die here -> free for rotation) --
        s16x8 xf0 = pack8(cx0, cx1);
        s16x8 xf1 = pack8(cx2, cx3);
        s16x8 bfrag;
        {
            union { u32x4 u; s16x8 v; } B;
            B.u[0] = cvtpk(cb.x, cb.y);
            B.u[1] = cvtpk(cb.z, cb.w);
            B.u[2] = 0; B.u[3] = 0;
            bfrag = B.v;
        }

        // ---- acc init = scaled biases ----
        f32x4 acc1[4], acc2[4];
        #pragma unroll
        for (int nb = 0; nb < 4; ++nb) {
            acc1[nb] = *(const f32x4*)&blds[nb * 16 + q * 4];
            acc2[nb] = *(const f32x4*)&blds[64 + nb * 16 + q * 4];
        }

        // ---- layer 1, atom part: kh 0..3 ----
        __builtin_amdgcn_s_setprio(1);
        #pragma unroll
        for (int nb = 0; nb < 4; ++nb) {
            s16x8 w;
            w = *(const s16x8*)&wlds[( 0 + nb) * 512 + lane * 8];
            acc1[nb] = __builtin_amdgcn_mfma_f32_16x16x32_bf16(w, ai0, acc1[nb], 0, 0, 0);
            w = *(const s16x8*)&wlds[( 4 + nb) * 512 + lane * 8];
            acc1[nb] = __builtin_amdgcn_mfma_f32_16x16x32_bf16(w, ai1, acc1[nb], 0, 0, 0);
            w = *(const s16x8*)&wlds[( 8 + nb) * 512 + lane * 8];
            acc1[nb] = __builtin_amdgcn_mfma_f32_16x16x32_bf16(w, aj0, acc1[nb], 0, 0, 0);
            w = *(const s16x8*)&wlds[(12 + nb) * 512 + lane * 8];
            acc1[nb] = __builtin_amdgcn_mfma_f32_16x16x32_bf16(w, aj1, acc1[nb], 0, 0, 0);
            w = *(const s16x8*)&wlds[(24 + nb) * 512 + lane * 8];
            acc2[nb] = __builtin_amdgcn_mfma_f32_16x16x32_bf16(w, ai0, acc2[nb], 0, 0, 0);
            w = *(const s16x8*)&wlds[(28 + nb) * 512 + lane * 8];
            acc2[nb] = __builtin_amdgcn_mfma_f32_16x16x32_bf16(w, ai1, acc2[nb], 0, 0, 0);
            w = *(const s16x8*)&wlds[(32 + nb) * 512 + lane * 8];
            acc2[nb] = __builtin_amdgcn_mfma_f32_16x16x32_bf16(w, aj0, acc2[nb], 0, 0, 0);
            w = *(const s16x8*)&wlds[(36 + nb) * 512 + lane * 8];
            acc2[nb] = __builtin_amdgcn_mfma_f32_16x16x32_bf16(w, aj1, acc2[nb], 0, 0, 0);
        }
        __builtin_amdgcn_s_setprio(0);

        // ---- prefetch: gathers T+1 (depth-1); streams depth-2 rotate ----
        const int T2 = Tn + tstride;
        const bool haveT2 = (T2 < tiles);
        s16x8 nai0 = ai0, nai1 = ai1, naj0 = aj0, naj1 = aj1;
        if (havenext) {
            nai0 = *(const s16x8*)&Af[(size_t)nbn.x * 64 + q * 8];
            nai1 = *(const s16x8*)&Af[(size_t)nbn.x * 64 + 32 + q * 8];
            naj0 = *(const s16x8*)&Af[(size_t)nbn.y * 64 + q * 8];
            naj1 = *(const s16x8*)&Af[(size_t)nbn.y * 64 + 32 + q * 8];
            if (haveT2) nbn = nb2[min(T2 * 16 + n, n_edges - 1)];
        }
        cx0 = nx0; cx1 = nx1; cx2 = nx2; cx3 = nx3; cb = nbd;
        if (haveT2) {
            const int e2 = min(T2 * 16 + n, n_edges - 1);
            const float* xr2 = edge_ij + (size_t)e2 * 64;
            nx0 = *(const float4*)(xr2 +      q * 4);
            nx1 = *(const float4*)(xr2 + 16 + q * 4);
            nx2 = *(const float4*)(xr2 + 32 + q * 4);
            nx3 = *(const float4*)(xr2 + 48 + q * 4);
            nbd = *(const float4*)(bonds_r + (size_t)e2 * 16 + q * 4);
        }

        // ---- layer 1, e_ij part: kh 4..5 ----
        __builtin_amdgcn_s_setprio(1);
        #pragma unroll
        for (int nb = 0; nb < 4; ++nb) {
            s16x8 w;
            w = *(const s16x8*)&wlds[(16 + nb) * 512 + lane * 8];
            acc1[nb] = __builtin_amdgcn_mfma_f32_16x16x32_bf16(w, xf0, acc1[nb], 0, 0, 0);
            w = *(const s16x8*)&wlds[(20 + nb) * 512 + lane * 8];
            acc1[nb] = __builtin_amdgcn_mfma_f32_16x16x32_bf16(w, xf1, acc1[nb], 0, 0, 0);
            acc2[nb] = __builtin_amdgcn_mfma_f32_16x16x32_bf16(w2e[nb],     xf0, acc2[nb], 0, 0, 0);
            acc2[nb] = __builtin_amdgcn_mfma_f32_16x16x32_bf16(w2e[4 + nb], xf1, acc2[nb], 0, 0, 0);
        }
        __builtin_amdgcn_s_setprio(0);

        // ---- h (x log2e) lane-local: a1s*rcp((1+2^-a1s)(1+2^-a2s)) ----
        f32x4 h[4];
        #pragma unroll
        for (int nb = 0; nb < 4; ++nb) {
            f32x4 s1 = acc1[nb], s2 = acc2[nb], hv;
            #pragma unroll
            for (int j = 0; j < 4; ++j) {
                float ea = exp2f_raw(-s1[j]);
                float eb = exp2f_raw(-s2[j]);
                hv[j] = s1[j] * __builtin_amdgcn_rcpf((1.0f + ea) * (1.0f + eb));
            }
            h[nb] = hv;
        }
        s16x8 hf0, hf1;
        {
            union { u32x4 u; s16x8 v; } H0, H1;
            H0.u[0] = cvtpk(h[0][0], h[0][1]);
            H0.u[1] = cvtpk(h[0][2], h[0][3]);
            H0.u[2] = cvtpk(h[1][0], h[1][1]);
            H0.u[3] = cvtpk(h[1][2], h[1][3]);
            H1.u[0] = cvtpk(h[2][0], h[2][1]);
            H1.u[1] = cvtpk(h[2][2], h[2][3]);
            H1.u[2] = cvtpk(h[3][0], h[3][1]);
            H1.u[3] = cvtpk(h[3][2], h[3][3]);
            hf0 = H0.v; hf1 = H1.v;
        }

        // ---- layer 2 (h*log2e @ W3 -> a3 pre-scaled) and gate (x ln2) ----
        f32x4 a3[4], g[4];
        #pragma unroll
        for (int nb = 0; nb < 4; ++nb) { a3[nb] = (f32x4){0,0,0,0}; g[nb] = (f32x4){0,0,0,0}; }
        __builtin_amdgcn_s_setprio(1);
        #pragma unroll
        for (int nb = 0; nb < 4; ++nb) {
            a3[nb] = __builtin_amdgcn_mfma_f32_16x16x32_bf16(hf0, w3f[nb],     a3[nb], 0, 0, 0);
            a3[nb] = __builtin_amdgcn_mfma_f32_16x16x32_bf16(hf1, w3f[4 + nb], a3[nb], 0, 0, 0);
            g[nb]  = __builtin_amdgcn_mfma_f32_16x16x32_bf16(bfrag, wrf[nb],   g[nb],  0, 0, 0);
        }
        __builtin_amdgcn_s_setprio(0);

        // ---- out = s_scaled * rcp(1+2^-s_scaled) * g'  (all folds done) --
        float* outp = out + (size_t)(E0 + q * 4) * 64 + n;
        if (E0 + 16 <= n_edges) {
            #pragma unroll
            for (int nb = 0; nb < 4; ++nb) {
                const float b3s = blds[128 + nb * 16 + n];
                const float brs = blds[192 + nb * 16 + n];
                f32x4 s  = a3[nb] + b3s;
                f32x4 gg = g[nb] + brs;
                f32x4 o;
                #pragma unroll
                for (int j = 0; j < 4; ++j)
                    o[j] = s[j] * sig2f(s[j]) * gg[j];
                #pragma unroll
                for (int j = 0; j < 4; ++j)
                    outp[j * 64 + nb * 16] = o[j];
            }
        } else {
            #pragma unroll
            for (int nb = 0; nb < 4; ++nb) {
                const float b3s = blds[128 + nb * 16 + n];
                const float brs = blds[192 + nb * 16 + n];
                f32x4 s  = a3[nb] + b3s;
                f32x4 gg = g[nb] + brs;
                #pragma unroll
                for (int j = 0; j < 4; ++j)
                    if (E0 + q * 4 + j < n_edges)
                        outp[j * 64 + nb * 16] = s[j] * sig2f(s[j]) * gg[j];
            }
        }

        if (!havenext) break;
        // ---- advance ----
        T = Tn;
        Tn = T2;
        havenext = (Tn < tiles);
        ai0 = nai0; ai1 = nai1; aj0 = naj0; aj1 = naj1;
    }
}

// ---------------------------------------------------------------------------
extern "C" void kernel_launch(void* const* d_in, const int* in_sizes, int n_in,
                              void* d_out, int out_size, void* d_ws, size_t ws_size,
                              hipStream_t stream) {
    const float* atom_fea = (const float*)d_in[0];
    const float* edge_ij  = (const float*)d_in[1];
    const int*   nbr      = (const int*)  d_in[2];
    const float* bonds_r  = (const float*)d_in[3];
    const float* W1 = (const float*)d_in[4];
    const float* b1 = (const float*)d_in[5];
    const float* W2 = (const float*)d_in[6];
    const float* b2 = (const float*)d_in[7];
    const float* Wr = (const float*)d_in[8];
    const float* br = (const float*)d_in[9];
    const float* W3 = (const float*)d_in[10];
    const float* b3 = (const float*)d_in[11];
    float* out = (float*)d_out;
    unsigned short* Af = (unsigned short*)d_ws;   // 50000*64 bf16 = 6.4 MB

    const int n_atoms = in_sizes[0] / 64;
    const int n_edges = in_sizes[2] / 2;

    hipLaunchKernelGGL(atom_conv_kernel, dim3(2048), dim3(256), 0, stream,
                       atom_fea, Af, n_atoms * 64);

    hipLaunchKernelGGL(edge_kernel, dim3(256), dim3(1024), 0, stream,
                       Af, edge_ij, nbr, bonds_r,
                       W1, b1, W2, b2, W3, b3, Wr, br, out, n_edges);
}

// Round 27
// 243.513 us; speedup vs baseline: 2.1340x; 2.1320x over previous
//
#include <hip/hip_runtime.h>
#include <hip/hip_bf16.h>

typedef float    f32x4 __attribute__((ext_vector_type(4)));
typedef short    s16x8 __attribute__((ext_vector_type(8)));
typedef unsigned u32x4 __attribute__((ext_vector_type(4)));

__device__ __forceinline__ unsigned short f2bf(float f) {
    union { __hip_bfloat16 b; unsigned short u; } v;
    v.b = __float2bfloat16(f);
    return v.u;
}
// HW packed f32->bf16 (RTNE, same as __float2bfloat16): 2 converts / 1 op.
__device__ __forceinline__ unsigned cvtpk(float lo, float hi) {
    unsigned r;
    asm("v_cvt_pk_bf16_f32 %0, %1, %2" : "=v"(r) : "v"(lo), "v"(hi));
    return r;
}
__device__ __forceinline__ float sigf(float x)  {
    return __builtin_amdgcn_rcpf(1.0f + __expf(-x));
}

__device__ __forceinline__ s16x8 pack8(float4 a, float4 b) {
    union { u32x4 u; s16x8 v; } r;
    r.u[0] = cvtpk(a.x, a.y);
    r.u[1] = cvtpk(a.z, a.w);
    r.u[2] = cvtpk(b.x, b.y);
    r.u[3] = cvtpk(b.z, b.w);
    return r.v;
}

// ---------------------------------------------------------------------------
// Kernel 1: convert atom_fea fp32 -> bf16, rows PERMUTED into B-fragment
// split-half order: Af[a][(kh*4+q)*8 + jj] = bf16(atom[a][kh*32 + q*4 +
// (jj&3) + (jj>=4 ? 16 : 0)]).  Each lane's fragment = one 16 B load.
// ---------------------------------------------------------------------------
__global__ __launch_bounds__(256) void atom_conv_kernel(
    const float* __restrict__ atom_fea, unsigned short* __restrict__ Af, int total)
{
    int i = blockIdx.x * blockDim.x + threadIdx.x;
    const int stride = gridDim.x * blockDim.x;
    for (; i < total; i += stride) {
        int a = i >> 6, p = i & 63;
        int kh = p >> 5, q = (p >> 3) & 3, jj = p & 7;
        int k = kh * 32 + q * 4 + (jj & 3) + ((jj & 4) ? 16 : 0);
        Af[i] = f2bf(atom_fea[(size_t)a * 64 + k]);
    }
}

// ---------------------------------------------------------------------------
// Kernel 2: FINAL = R21 config, the verified best (243.8 us): 512 thr /
// (512,2), NCH=40 LDS weights + W3/Wr/W2e register weights, merged-rcp h,
// setprio around MFMA clusters, depth-1 gather + depth-2 stream prefetch.
// VGPR 108, no spill (WRITE == 400.0 MB), occupancy 8 waves/CU.
// R23-R26 proved the toolchain refuses {16 waves + >=108 VGPR} via every
// available knob (launch-bounds, LDS pad, waves_per_eu, num_vgpr — all
// left VGPR at 64 -> 123 MB scratch -> 519 us), so this envelope is the
// structural floor: latency-bound with HBM 41% / VALU 34% / MFMA 16%.
// ---------------------------------------------------------------------------
#define NCH 40

__global__ __launch_bounds__(512, 2) void edge_kernel(
    const unsigned short* __restrict__ Af,
    const float* __restrict__ edge_ij,
    const int*   __restrict__ nbr,
    const float* __restrict__ bonds_r,
    const float* __restrict__ W1, const float* __restrict__ b1,
    const float* __restrict__ W2, const float* __restrict__ b2,
    const float* __restrict__ W3, const float* __restrict__ b3,
    const float* __restrict__ Wr, const float* __restrict__ br,
    float* __restrict__ out, int n_edges)
{
    __shared__ unsigned short wlds[NCH * 512];   // 40 KiB: W1 all + W2 atom
    __shared__ float blds[256];                  // b1 | b2 | b3 | br

    const int t    = threadIdx.x;
    const int wave = t >> 6;
    const int lane = t & 63;
    const int q    = lane >> 4;
    const int n    = lane & 15;

    // ---- stage W1 (24 chunks) + W2 atom-part (16 chunks): t<256 only ----
    if (t < 256) {
        for (int ch = 0; ch < NCH; ++ch) {
            int idx = t * 2;
            #pragma unroll
            for (int e2 = 0; e2 < 2; ++e2, ++idx) {
                const int l  = idx >> 3, j = idx & 7;
                const int lq = l >> 4, ln = l & 15;
                const int kk = (j < 4) ? (lq * 4 + j) : (16 + lq * 4 + (j - 4));
                float val;
                if (ch < 24) {                       // W1: kh 0..5, nb 0..3
                    int kh = ch >> 2, nb = ch & 3;
                    val = W1[(size_t)(kh * 32 + kk) * 64 + nb * 16 + ln];
                } else {                             // W2 atom part: kh 0..3
                    int c2 = ch - 24; int kh = c2 >> 2, nb = c2 & 3;
                    val = W2[(size_t)(kh * 32 + kk) * 64 + nb * 16 + ln];
                }
                wlds[ch * 512 + idx] = f2bf(val);
            }
        }
        if (t < 64)        blds[t] = b1[t];
        else if (t < 128)  blds[t] = b2[t - 64];
        else if (t < 192)  blds[t] = b3[t - 128];
        else               blds[t] = br[t - 192];
    }

    // ---- W3 / Wr / W2-e_ij fragments persistent in registers ----
    s16x8 w3f[8], wrf[4], w2e[8];
    {
        const int ln = lane & 15;
        const int lq = lane >> 4;
        #pragma unroll
        for (int c2 = 0; c2 < 8; ++c2) {
            const int kh = c2 >> 2, nb = c2 & 3;
            s16x8 w, v;
            #pragma unroll
            for (int j = 0; j < 8; ++j) {
                const int kk = (j < 4) ? (lq * 4 + j) : (16 + lq * 4 + (j - 4));
                w[j] = (short)f2bf(W3[(size_t)(kh * 32 + kk) * 64 + nb * 16 + ln]);
                v[j] = (short)f2bf(W2[(size_t)((kh + 4) * 32 + kk) * 64 + nb * 16 + ln]);
            }
            w3f[c2] = w;
            w2e[c2] = v;
        }
        #pragma unroll
        for (int nb = 0; nb < 4; ++nb) {
            s16x8 w;
            #pragma unroll
            for (int j = 0; j < 8; ++j) {
                const int kk = (j < 4) ? (lq * 4 + j) : (16 + lq * 4 + (j - 4));
                w[j] = (short)(kk < 16 ? f2bf(Wr[(size_t)kk * 64 + nb * 16 + ln]) : 0);
            }
            wrf[nb] = w;
        }
    }
    __syncthreads();

    const int tiles   = (n_edges + 15) >> 4;
    const int tstride = gridDim.x * 8;
    int T = blockIdx.x * 8 + wave;
    if (T >= tiles) return;

    const int2* nb2 = (const int2*)nbr;

    // ---- prologue: gathers for T; streams for T (cur) and T+s (next) ----
    int Tn = T + tstride;
    bool havenext = (Tn < tiles);
    int2 nbc = nb2[min(T * 16 + n, n_edges - 1)];
    int2 nbn = nbc;
    if (havenext) nbn = nb2[min(Tn * 16 + n, n_edges - 1)];

    s16x8 ai0 = *(const s16x8*)&Af[(size_t)nbc.x * 64 + q * 8];
    s16x8 ai1 = *(const s16x8*)&Af[(size_t)nbc.x * 64 + 32 + q * 8];
    s16x8 aj0 = *(const s16x8*)&Af[(size_t)nbc.y * 64 + q * 8];
    s16x8 aj1 = *(const s16x8*)&Af[(size_t)nbc.y * 64 + 32 + q * 8];

    const int e0 = min(T * 16 + n, n_edges - 1);
    const float* xr0 = edge_ij + (size_t)e0 * 64;
    float4 cx0 = *(const float4*)(xr0 +      q * 4);
    float4 cx1 = *(const float4*)(xr0 + 16 + q * 4);
    float4 cx2 = *(const float4*)(xr0 + 32 + q * 4);
    float4 cx3 = *(const float4*)(xr0 + 48 + q * 4);
    float4 cb  = *(const float4*)(bonds_r + (size_t)e0 * 16 + q * 4);

    const int e1 = havenext ? min(Tn * 16 + n, n_edges - 1) : e0;
    const float* xr1 = edge_ij + (size_t)e1 * 64;
    float4 nx0 = *(const float4*)(xr1 +      q * 4);
    float4 nx1 = *(const float4*)(xr1 + 16 + q * 4);
    float4 nx2 = *(const float4*)(xr1 + 32 + q * 4);
    float4 nx3 = *(const float4*)(xr1 + 48 + q * 4);
    float4 nbd = *(const float4*)(bonds_r + (size_t)e1 * 16 + q * 4);

    while (true) {
        const int E0 = T * 16;

        // ---- pack current streams (cx/cb die here -> free for rotation) --
        s16x8 xf0 = pack8(cx0, cx1);
        s16x8 xf1 = pack8(cx2, cx3);
        s16x8 bfrag;
        {
            union { u32x4 u; s16x8 v; } B;
            B.u[0] = cvtpk(cb.x, cb.y);
            B.u[1] = cvtpk(cb.z, cb.w);
            B.u[2] = 0; B.u[3] = 0;
            bfrag = B.v;
        }

        // ---- acc init = biases ----
        f32x4 acc1[4], acc2[4];
        #pragma unroll
        for (int nb = 0; nb < 4; ++nb) {
            acc1[nb] = *(const f32x4*)&blds[nb * 16 + q * 4];
            acc2[nb] = *(const f32x4*)&blds[64 + nb * 16 + q * 4];
        }

        // ---- layer 1, atom part: kh 0..3 ----
        __builtin_amdgcn_s_setprio(1);
        #pragma unroll
        for (int nb = 0; nb < 4; ++nb) {
            s16x8 w;
            w = *(const s16x8*)&wlds[( 0 + nb) * 512 + lane * 8];
            acc1[nb] = __builtin_amdgcn_mfma_f32_16x16x32_bf16(w, ai0, acc1[nb], 0, 0, 0);
            w = *(const s16x8*)&wlds[( 4 + nb) * 512 + lane * 8];
            acc1[nb] = __builtin_amdgcn_mfma_f32_16x16x32_bf16(w, ai1, acc1[nb], 0, 0, 0);
            w = *(const s16x8*)&wlds[( 8 + nb) * 512 + lane * 8];
            acc1[nb] = __builtin_amdgcn_mfma_f32_16x16x32_bf16(w, aj0, acc1[nb], 0, 0, 0);
            w = *(const s16x8*)&wlds[(12 + nb) * 512 + lane * 8];
            acc1[nb] = __builtin_amdgcn_mfma_f32_16x16x32_bf16(w, aj1, acc1[nb], 0, 0, 0);
            w = *(const s16x8*)&wlds[(24 + nb) * 512 + lane * 8];
            acc2[nb] = __builtin_amdgcn_mfma_f32_16x16x32_bf16(w, ai0, acc2[nb], 0, 0, 0);
            w = *(const s16x8*)&wlds[(28 + nb) * 512 + lane * 8];
            acc2[nb] = __builtin_amdgcn_mfma_f32_16x16x32_bf16(w, ai1, acc2[nb], 0, 0, 0);
            w = *(const s16x8*)&wlds[(32 + nb) * 512 + lane * 8];
            acc2[nb] = __builtin_amdgcn_mfma_f32_16x16x32_bf16(w, aj0, acc2[nb], 0, 0, 0);
            w = *(const s16x8*)&wlds[(36 + nb) * 512 + lane * 8];
            acc2[nb] = __builtin_amdgcn_mfma_f32_16x16x32_bf16(w, aj1, acc2[nb], 0, 0, 0);
        }
        __builtin_amdgcn_s_setprio(0);

        // ---- prefetch: gathers for T+1 (depth-1); streams rotate to
        //      depth-2 — copy next->cur, then issue T+2 into next ----
        const int T2 = Tn + tstride;
        const bool haveT2 = (T2 < tiles);
        s16x8 nai0 = ai0, nai1 = ai1, naj0 = aj0, naj1 = aj1;
        if (havenext) {
            nai0 = *(const s16x8*)&Af[(size_t)nbn.x * 64 + q * 8];
            nai1 = *(const s16x8*)&Af[(size_t)nbn.x * 64 + 32 + q * 8];
            naj0 = *(const s16x8*)&Af[(size_t)nbn.y * 64 + q * 8];
            naj1 = *(const s16x8*)&Af[(size_t)nbn.y * 64 + 32 + q * 8];
            if (haveT2) nbn = nb2[min(T2 * 16 + n, n_edges - 1)];
        }
        // rotate streams (cx dead since pack8): cur <- next
        cx0 = nx0; cx1 = nx1; cx2 = nx2; cx3 = nx3; cb = nbd;
        if (haveT2) {
            const int e2 = min(T2 * 16 + n, n_edges - 1);
            const float* xr2 = edge_ij + (size_t)e2 * 64;
            nx0 = *(const float4*)(xr2 +      q * 4);
            nx1 = *(const float4*)(xr2 + 16 + q * 4);
            nx2 = *(const float4*)(xr2 + 32 + q * 4);
            nx3 = *(const float4*)(xr2 + 48 + q * 4);
            nbd = *(const float4*)(bonds_r + (size_t)e2 * 16 + q * 4);
        }

        // ---- layer 1, e_ij part: kh 4..5 ----
        __builtin_amdgcn_s_setprio(1);
        #pragma unroll
        for (int nb = 0; nb < 4; ++nb) {
            s16x8 w;
            w = *(const s16x8*)&wlds[(16 + nb) * 512 + lane * 8];
            acc1[nb] = __builtin_amdgcn_mfma_f32_16x16x32_bf16(w, xf0, acc1[nb], 0, 0, 0);
            w = *(const s16x8*)&wlds[(20 + nb) * 512 + lane * 8];
            acc1[nb] = __builtin_amdgcn_mfma_f32_16x16x32_bf16(w, xf1, acc1[nb], 0, 0, 0);
            acc2[nb] = __builtin_amdgcn_mfma_f32_16x16x32_bf16(w2e[nb],     xf0, acc2[nb], 0, 0, 0);
            acc2[nb] = __builtin_amdgcn_mfma_f32_16x16x32_bf16(w2e[4 + nb], xf1, acc2[nb], 0, 0, 0);
        }
        __builtin_amdgcn_s_setprio(0);

        // ---- h lane-local, merged rcp: a1*rcp((1+e^-a1)(1+e^-a2)) ----
        f32x4 h[4];
        #pragma unroll
        for (int nb = 0; nb < 4; ++nb) {
            f32x4 s1 = acc1[nb], s2 = acc2[nb], hv;
            #pragma unroll
            for (int j = 0; j < 4; ++j) {
                float ea = __expf(-s1[j]);
                float eb = __expf(-s2[j]);
                hv[j] = s1[j] * __builtin_amdgcn_rcpf((1.0f + ea) * (1.0f + eb));
            }
            h[nb] = hv;
        }
        s16x8 hf0, hf1;
        {
            union { u32x4 u; s16x8 v; } H0, H1;
            H0.u[0] = cvtpk(h[0][0], h[0][1]);
            H0.u[1] = cvtpk(h[0][2], h[0][3]);
            H0.u[2] = cvtpk(h[1][0], h[1][1]);
            H0.u[3] = cvtpk(h[1][2], h[1][3]);
            H1.u[0] = cvtpk(h[2][0], h[2][1]);
            H1.u[1] = cvtpk(h[2][2], h[2][3]);
            H1.u[2] = cvtpk(h[3][0], h[3][1]);
            H1.u[3] = cvtpk(h[3][2], h[3][3]);
            hf0 = H0.v; hf1 = H1.v;
        }

        // ---- layer 2 (h @ W3) and gate (bonds @ Wr): register weights ----
        f32x4 a3[4], g[4];
        #pragma unroll
        for (int nb = 0; nb < 4; ++nb) { a3[nb] = (f32x4){0,0,0,0}; g[nb] = (f32x4){0,0,0,0}; }
        __builtin_amdgcn_s_setprio(1);
        #pragma unroll
        for (int nb = 0; nb < 4; ++nb) {
            a3[nb] = __builtin_amdgcn_mfma_f32_16x16x32_bf16(hf0, w3f[nb],     a3[nb], 0, 0, 0);
            a3[nb] = __builtin_amdgcn_mfma_f32_16x16x32_bf16(hf1, w3f[4 + nb], a3[nb], 0, 0, 0);
            g[nb]  = __builtin_amdgcn_mfma_f32_16x16x32_bf16(bfrag, wrf[nb],   g[nb],  0, 0, 0);
        }
        __builtin_amdgcn_s_setprio(0);

        // ---- out[edge q*4+j][oc nb*16+n] = silu(a3+b3)*(g+br) ----
        float* outp = out + (size_t)(E0 + q * 4) * 64 + n;
        if (E0 + 16 <= n_edges) {
            #pragma unroll
            for (int nb = 0; nb < 4; ++nb) {
                const float b3s = blds[128 + nb * 16 + n];
                const float brs = blds[192 + nb * 16 + n];
                f32x4 s  = a3[nb] + b3s;
                f32x4 gg = g[nb] + brs;
                f32x4 o;
                #pragma unroll
                for (int j = 0; j < 4; ++j)
                    o[j] = s[j] * sigf(s[j]) * gg[j];
                #pragma unroll
                for (int j = 0; j < 4; ++j)
                    outp[j * 64 + nb * 16] = o[j];
            }
        } else {
            #pragma unroll
            for (int nb = 0; nb < 4; ++nb) {
                const float b3s = blds[128 + nb * 16 + n];
                const float brs = blds[192 + nb * 16 + n];
                f32x4 s  = a3[nb] + b3s;
                f32x4 gg = g[nb] + brs;
                #pragma unroll
                for (int j = 0; j < 4; ++j)
                    if (E0 + q * 4 + j < n_edges)
                        outp[j * 64 + nb * 16] = s[j] * sigf(s[j]) * gg[j];
            }
        }

        if (!havenext) break;
        // ---- advance ----
        T = Tn;
        Tn = T2;
        havenext = (Tn < tiles);
        ai0 = nai0; ai1 = nai1; aj0 = naj0; aj1 = naj1;
    }
}

// ---------------------------------------------------------------------------
extern "C" void kernel_launch(void* const* d_in, const int* in_sizes, int n_in,
                              void* d_out, int out_size, void* d_ws, size_t ws_size,
                              hipStream_t stream) {
    const float* atom_fea = (const float*)d_in[0];
    const float* edge_ij  = (const float*)d_in[1];
    const int*   nbr      = (const int*)  d_in[2];
    const float* bonds_r  = (const float*)d_in[3];
    const float* W1 = (const float*)d_in[4];
    const float* b1 = (const float*)d_in[5];
    const float* W2 = (const float*)d_in[6];
    const float* b2 = (const float*)d_in[7];
    const float* Wr = (const float*)d_in[8];
    const float* br = (const float*)d_in[9];
    const float* W3 = (const float*)d_in[10];
    const float* b3 = (const float*)d_in[11];
    float* out = (float*)d_out;
    unsigned short* Af = (unsigned short*)d_ws;   // 50000*64 bf16 = 6.4 MB

    const int n_atoms = in_sizes[0] / 64;
    const int n_edges = in_sizes[2] / 2;

    hipLaunchKernelGGL(atom_conv_kernel, dim3(2048), dim3(256), 0, stream,
                       atom_fea, Af, n_atoms * 64);

    hipLaunchKernelGGL(edge_kernel, dim3(512), dim3(512), 0, stream,
                       Af, edge_ij, nbr, bonds_r,
                       W1, b1, W2, b2, W3, b3, Wr, br, out, n_edges);
}